// Round 1
// baseline (198.564 us; speedup 1.0000x reference)
//
#include <hip/hip_runtime.h>

typedef __bf16 bf16;
typedef __bf16 bf16x8 __attribute__((ext_vector_type(8)));
typedef float f32x4 __attribute__((ext_vector_type(4)));

#define K_ME 2080  // 2048 (x*g) + 8 (bias via g/pb) + 24 zero pad

__device__ __forceinline__ f32x4 mfma16(bf16x8 a, bf16x8 b, f32x4 c) {
  return __builtin_amdgcn_mfma_f32_16x16x32_bf16(a, b, c, 0, 0, 0);
}

// ---------------- gating: g = softmax(x@gw+gb); xgb[b][i*8+l] = bf16(x[b,i]*g[b,l]),
// cols 2048..2055 = g (bias fold), 2056..2079 = 0 ----------------
__global__ __launch_bounds__(256) void gating_kernel(
    const float* __restrict__ x, const float* __restrict__ gw,
    const float* __restrict__ gb, bf16* __restrict__ xgb) {
  const int b = blockIdx.x, tid = threadIdx.x;
  __shared__ float xs[256];
  __shared__ float gs[8];
  xs[tid] = x[b * 256 + tid];
  __syncthreads();
  if (tid < 8) {
    float acc = gb[tid];
    for (int i = 0; i < 256; ++i) acc += xs[i] * gw[i * 8 + tid];
    gs[tid] = acc;
  }
  __syncthreads();
  if (tid == 0) {
    float m = gs[0];
    for (int l = 1; l < 8; ++l) m = fmaxf(m, gs[l]);
    float s = 0.f, e[8];
    for (int l = 0; l < 8; ++l) { e[l] = expf(gs[l] - m); s += e[l]; }
    float inv = 1.f / s;
    for (int l = 0; l < 8; ++l) gs[l] = e[l] * inv;
  }
  __syncthreads();
  bf16* dst = xgb + (size_t)b * K_ME;
  for (int k = tid; k < K_ME; k += 256) {
    float v;
    if (k < 2048)      v = xs[k >> 3] * gs[k & 7];
    else if (k < 2056) v = gs[k - 2048];
    else               v = 0.f;
    dst[k] = (bf16)v;
  }
}

// ---------------- pw (8192,256,8) f32 -> pwb[o][2080] bf16 (cols 2048..2055 = pb[o][l]) ----
__global__ __launch_bounds__(256) void convert_pw_kernel(
    const float* __restrict__ pw, const float* __restrict__ pb,
    bf16* __restrict__ pwb) {
  const int o = blockIdx.x, t = threadIdx.x;
  const float4* src = (const float4*)(pw + (size_t)o * 2048);
  float4 v0 = src[2 * t], v1 = src[2 * t + 1];
  bf16x8 r;
  r[0] = (bf16)v0.x; r[1] = (bf16)v0.y; r[2] = (bf16)v0.z; r[3] = (bf16)v0.w;
  r[4] = (bf16)v1.x; r[5] = (bf16)v1.y; r[6] = (bf16)v1.z; r[7] = (bf16)v1.w;
  *(bf16x8*)(pwb + (size_t)o * K_ME + t * 8) = r;
  if (t < 8)       pwb[(size_t)o * K_ME + 2048 + t] = (bf16)pb[o * 8 + t];
  else if (t < 32) pwb[(size_t)o * K_ME + 2048 + t] = (bf16)0.f;
}

// ---------------- weight transform: w (CIN,COUT,4,4) -> wp[p][ocp][t*CIN+ic] bf16 --------
// parity p=(py,px); tap t=(tyi,txi): py=0 -> ky in {1,3} (dy 0,-1); py=1 -> ky in {0,2} (dy +1,0)
template <int CIN, int COUT, int COUTP>
__global__ __launch_bounds__(256) void convert_w_kernel(
    const float* __restrict__ w, bf16* __restrict__ wp) {
  constexpr int K = 4 * CIN;
  constexpr int total = 4 * COUTP * K;
  int idx = blockIdx.x * 256 + threadIdx.x;
  if (idx >= total) return;
  int ic = idx & (CIN - 1);
  int t = (idx / CIN) & 3;
  int oc = (idx / K) % COUTP;
  int p = idx / (K * COUTP);
  bf16 v = (bf16)0.f;
  if (oc < COUT) {
    int py = p >> 1, px = p & 1, tyi = t >> 1, txi = t & 1;
    int ky = py == 0 ? (tyi ? 3 : 1) : (tyi ? 2 : 0);
    int kx = px == 0 ? (txi ? 3 : 1) : (txi ? 2 : 0);
    v = (bf16)w[((ic * COUT + oc) * 4 + ky) * 4 + kx];
  }
  wp[idx] = v;
}

// ---------------- ME GEMM: C[b,o] = XG[b,:] . PWB[o,:]; epilogue -> h0t (B,10,10,128) bf16 pad
// block = 64b x 64o, 4 waves in 2x2; wave tile 32x32 (m2 x n2)
__global__ __launch_bounds__(256) void me_gemm_kernel(
    const bf16* __restrict__ xgb, const bf16* __restrict__ pwb,
    bf16* __restrict__ h0t) {
  const int tid = threadIdx.x, wv = tid >> 6, l = tid & 63;
  const int lr = l & 15, lkg = l >> 4;
  const int b0 = blockIdx.y * 64 + (wv >> 1) * 32;
  const int o0 = blockIdx.x * 64 + (wv & 1) * 32;
  const bf16* arow0 = xgb + (size_t)(b0 + lr) * K_ME + lkg * 8;
  const bf16* arow1 = arow0 + 16 * K_ME;
  const bf16* brow0 = pwb + (size_t)(o0 + lr) * K_ME + lkg * 8;
  const bf16* brow1 = brow0 + 16 * K_ME;
  f32x4 acc[2][2] = {};
#pragma unroll 4
  for (int kk = 0; kk < K_ME; kk += 32) {
    bf16x8 a0 = *(const bf16x8*)(arow0 + kk);
    bf16x8 a1 = *(const bf16x8*)(arow1 + kk);
    bf16x8 q0 = *(const bf16x8*)(brow0 + kk);
    bf16x8 q1 = *(const bf16x8*)(brow1 + kk);
    acc[0][0] = mfma16(a0, q0, acc[0][0]);
    acc[0][1] = mfma16(a0, q1, acc[0][1]);
    acc[1][0] = mfma16(a1, q0, acc[1][0]);
    acc[1][1] = mfma16(a1, q1, acc[1][1]);
  }
  // C/D layout: col = l&15 (o), row = (l>>4)*4 + reg (b)
  for (int m = 0; m < 2; ++m)
    for (int n = 0; n < 2; ++n)
      for (int r = 0; r < 4; ++r) {
        int brow = b0 + m * 16 + lkg * 4 + r;
        int o = o0 + n * 16 + lr;
        int c = o >> 6, y = (o >> 3) & 7, xx = o & 7;
        h0t[((size_t)(brow * 10 + y + 1) * 10 + xx + 1) * 128 + c] = (bf16)acc[m][n][r];
      }
}

// ---------------- conv-transpose parity GEMM ----------------
// in: padded channels-last (B, HIN+2, WIN+2, CIN) bf16; out: padded (B, 2HIN+2, 2WIN+2, COUTP) bf16
// M = B*HIN*WIN rows (b,y',x'); N = COUTP; K = 4*CIN. block = 128 rows (4 waves x 32), wave m2 x nNF
template <int CIN, int HIN, int WIN, int COUTP, int NF, bool RELU, bool F32OUT>
__global__ __launch_bounds__(256) void convt_kernel(
    const bf16* __restrict__ in, const bf16* __restrict__ wp,
    const float* __restrict__ bias, bf16* __restrict__ out,
    float* __restrict__ fout) {
  constexpr int K = 4 * CIN;
  constexpr int HP = HIN + 2, WPD = WIN + 2;
  constexpr int HW = HIN * WIN;
  constexpr int OH = 2 * HIN, OW = 2 * WIN;
  constexpr int OHP = OH + 2, OWP = OW + 2;
  const int p = blockIdx.y, py = p >> 1, px = p & 1;
  const int tid = threadIdx.x, wv = tid >> 6, l = tid & 63;
  const int lr = l & 15, lkg = l >> 4;
  const int row0 = blockIdx.x * 128 + wv * 32;

  int abase[2];
#pragma unroll
  for (int m = 0; m < 2; ++m) {
    int r = row0 + m * 16 + lr;
    int b = r / HW, rem = r % HW;
    int y = rem / WIN, xx = rem % WIN;
    abase[m] = ((b * HP + y + 1) * WPD + xx + 1) * CIN;  // halo-centered
  }
  f32x4 acc[2][NF] = {};
#pragma unroll 2
  for (int kk = 0; kk < K; kk += 32) {
    int k = kk + lkg * 8;
    int t = k / CIN, ic = k % CIN;
    int tyi = t >> 1, txi = t & 1;
    int dy = (py == 0) ? (tyi ? -1 : 0) : (tyi ? 0 : 1);
    int dx = (px == 0) ? (txi ? -1 : 0) : (txi ? 0 : 1);
    int aoff = (dy * WPD + dx) * CIN + ic;
    bf16x8 av[2], bv[NF];
#pragma unroll
    for (int m = 0; m < 2; ++m) av[m] = *(const bf16x8*)(in + abase[m] + aoff);
#pragma unroll
    for (int n = 0; n < NF; ++n)
      bv[n] = *(const bf16x8*)(wp + (size_t)(p * COUTP + n * 16 + lr) * K + k);
#pragma unroll
    for (int m = 0; m < 2; ++m)
#pragma unroll
      for (int n = 0; n < NF; ++n) acc[m][n] = mfma16(av[m], bv[n], acc[m][n]);
  }
#pragma unroll
  for (int m = 0; m < 2; ++m)
#pragma unroll
    for (int r4 = 0; r4 < 4; ++r4) {
      int row = row0 + m * 16 + lkg * 4 + r4;
      int b = row / HW, rem = row % HW;
      int y = rem / WIN, xx = rem % WIN;
      int oy = 2 * y + py, ox = 2 * xx + px;
#pragma unroll
      for (int n = 0; n < NF; ++n) {
        int oc = n * 16 + lr;
        float v = acc[m][n][r4];
        if constexpr (F32OUT) {
          if (oc < 3) fout[((size_t)(b * 3 + oc) * OH + oy) * OW + ox] = v + bias[oc];
        } else {
          v += bias[oc];
          if constexpr (RELU) v = fmaxf(v, 0.f);
          out[((size_t)(b * OHP + oy + 1) * OWP + ox + 1) * COUTP + oc] = (bf16)v;
        }
      }
    }
}

// ---------------- launch ----------------
extern "C" void kernel_launch(void* const* d_in, const int* in_sizes, int n_in,
                              void* d_out, int out_size, void* d_ws, size_t ws_size,
                              hipStream_t stream) {
  const float* x  = (const float*)d_in[0];
  const float* gw = (const float*)d_in[1];
  const float* gb = (const float*)d_in[2];
  const float* pw = (const float*)d_in[3];
  const float* pb = (const float*)d_in[4];
  const float* w1 = (const float*)d_in[5];
  const float* b1 = (const float*)d_in[6];
  const float* w2 = (const float*)d_in[7];
  const float* b2 = (const float*)d_in[8];
  const float* w3 = (const float*)d_in[9];
  const float* b3 = (const float*)d_in[10];
  float* outp = (float*)d_out;

  char* ws = (char*)d_ws;
  bf16* xgb = (bf16*)(ws + 0);          // 256*2080*2      = 1,064,960
  bf16* pwb = (bf16*)(ws + 1064960);    // 8192*2080*2     = 34,078,720
  bf16* h0t = (bf16*)(ws + 35143680);   // 256*10*10*128*2 = 6,553,600
  bf16* w1p = (bf16*)(ws + 41697280);   // 4*64*512*2      = 262,144
  bf16* h1  = (bf16*)(ws + 41959424);   // 256*18*18*64*2  = 10,616,832
  bf16* w2p = (bf16*)(ws + 52576256);   // 4*32*256*2      = 65,536
  bf16* h2  = (bf16*)(ws + 52641792);   // 256*34*34*32*2  = 18,939,904
  bf16* w3p = (bf16*)(ws + 71581696);   // 4*16*128*2      = 16,384  (end 71,598,080)

  // zero halo'd activation buffers (borders must be 0 every call)
  hipMemsetAsync(h0t, 0, 6553600, stream);
  hipMemsetAsync(h1, 0, 10616832, stream);
  hipMemsetAsync(h2, 0, 18939904, stream);

  gating_kernel<<<256, 256, 0, stream>>>(x, gw, gb, xgb);
  convert_pw_kernel<<<8192, 256, 0, stream>>>(pw, pb, pwb);
  convert_w_kernel<128, 64, 64><<<512, 256, 0, stream>>>(w1, w1p);
  convert_w_kernel<64, 32, 32><<<128, 256, 0, stream>>>(w2, w2p);
  convert_w_kernel<32, 3, 16><<<32, 256, 0, stream>>>(w3, w3p);

  me_gemm_kernel<<<dim3(128, 4), 256, 0, stream>>>(xgb, pwb, h0t);

  convt_kernel<128, 8, 8, 64, 4, true, false>
      <<<dim3(128, 4), 256, 0, stream>>>(h0t, w1p, b1, h1, nullptr);
  convt_kernel<64, 16, 16, 32, 2, true, false>
      <<<dim3(512, 4), 256, 0, stream>>>(h1, w2p, b2, h2, nullptr);
  convt_kernel<32, 32, 32, 16, 1, false, true>
      <<<dim3(2048, 4), 256, 0, stream>>>(h2, w3p, b3, nullptr, outp);
}